// Round 13
// baseline (53.815 us; speedup 1.0000x reference)
//
#include <hip/hip_runtime.h>

#define NN    4096
#define MM    8191   // 2*NN - 1
#define BB    256
#define CAP   256    // u16 slots per HALF-row list (nnz/half ~20, max ~50)

typedef float nfloat4 __attribute__((ext_vector_type(4)));

__device__ __forceinline__ int prefix_lt(unsigned long long m) {
    return __builtin_amdgcn_mbcnt_hi((unsigned)(m >> 32),
           __builtin_amdgcn_mbcnt_lo((unsigned)m, 0u));
}

// round-to-nearest-even pack of two f32 into 2x bf16 in one uint
__device__ __forceinline__ unsigned pack2bf(float lo, float hi) {
    unsigned a = __float_as_uint(lo);
    unsigned b = __float_as_uint(hi);
    a += 0x7fffu + ((a >> 16) & 1u);
    b += 0x7fffu + ((b >> 16) & 1u);
    return (a >> 16) | (b & 0xffff0000u);
}

// ---------------------------------------------------------------------------
// k_prep: zero part2[256*256]; pack dd = bf16(d1-d2) (2 MB). One uint2/thread.
// ---------------------------------------------------------------------------
__global__ __launch_bounds__(256) void k_prep(const float4* __restrict__ d1,
                                              const float4* __restrict__ d2,
                                              float* __restrict__ part2,
                                              uint2* __restrict__ ddp) {
    int idx = blockIdx.x * 256 + threadIdx.x;          // 0..262143
    if (idx < 256 * BB) part2[idx] = 0.0f;
    float4 a = d1[idx], b = d2[idx];
    uint2 r;
    r.x = pack2bf(a.x - b.x, a.y - b.y);
    r.y = pack2bf(a.z - b.z, a.w - b.w);
    ddp[idx] = r;
}

// ---------------------------------------------------------------------------
// k_fused v2: 512 blocks x 4 waves; wave g owns rows m = g + k*2048 (k<4).
// Half-row register double-buffer pipeline (R12 post-mortem: serialized
// scan->gather phases left HBM at 30% duty):
//   wait A -> issue B (next half, nontemporal) -> compact A (VALU, B in
//   flight) -> gather A's indices from L2-resident dd (B still in flight)
//   -> swap. HBM stays saturated; gather+compact hide under the HBM service
//   window. nt loads keep the 134 MB stream from evicting the 2 MB dd.
// ---------------------------------------------------------------------------
__global__ __launch_bounds__(256, 4) void k_fused(
        const nfloat4* __restrict__ st4,
        const uint2* __restrict__ ddp,
        const float* __restrict__ param,
        const int*   __restrict__ parents,
        float* __restrict__ part2) {
    __shared__ unsigned short s_idx[4][CAP];   // per-wave half-row index list
    __shared__ float s_part[BB];
    const int tid  = threadIdx.x;
    const int wave = tid >> 6;
    const int lane = tid & 63;
    unsigned short* buf = s_idx[wave];

    s_part[tid] = 0.0f;
    __syncthreads();

    const int g = blockIdx.x * 4 + wave;       // 0..2047
    float p0 = 0.f, p1 = 0.f, p2 = 0.f, p3 = 0.f;

    nfloat4 a0, a1, a2, a3, a4, a5, a6, a7;
    nfloat4 b0, b1, b2, b3, b4, b5, b6, b7;

    #define ISSUE(P, m, h)                                                   \
    {                                                                        \
        const nfloat4* base = st4 + (size_t)(m) * (NN / 4) + (h) * (NN / 8); \
        P##0 = __builtin_nontemporal_load(base + lane);                      \
        P##1 = __builtin_nontemporal_load(base + 64  + lane);                \
        P##2 = __builtin_nontemporal_load(base + 128 + lane);                \
        P##3 = __builtin_nontemporal_load(base + 192 + lane);                \
        P##4 = __builtin_nontemporal_load(base + 256 + lane);                \
        P##5 = __builtin_nontemporal_load(base + 320 + lane);                \
        P##6 = __builtin_nontemporal_load(base + 384 + lane);                \
        P##7 = __builtin_nontemporal_load(base + 448 + lane);                \
    }
    #define SITE(val, col)                                                   \
    {                                                                        \
        unsigned long long mk = __ballot((val) != 0.0f);                     \
        if ((val) != 0.0f)                                                   \
            buf[c + prefix_lt(mk)] = (unsigned short)(col);                  \
        c += __popcll(mk);                                                   \
    }
    #define QUAD(v, cb0)                                                     \
        SITE(v.x, (cb0))     SITE(v.y, (cb0) + 1)                            \
        SITE(v.z, (cb0) + 2) SITE(v.w, (cb0) + 3)
    #define COMPACT(P, h)                                                    \
    {                                                                        \
        const int cb = (h) * (NN / 2);                                       \
        QUAD(P##0, cb + (lane)       * 4)                                    \
        QUAD(P##1, cb + (64  + lane) * 4)                                    \
        QUAD(P##2, cb + (128 + lane) * 4)                                    \
        QUAD(P##3, cb + (192 + lane) * 4)                                    \
        QUAD(P##4, cb + (256 + lane) * 4)                                    \
        QUAD(P##5, cb + (320 + lane) * 4)                                    \
        QUAD(P##6, cb + (384 + lane) * 4)                                    \
        QUAD(P##7, cb + (448 + lane) * 4)                                    \
    }
    #define UNP0(u) __uint_as_float((u) << 16)
    #define UNP1(u) __uint_as_float((u) & 0xffff0000u)
    #define ACCA(g) { c0 += UNP0(g.x); c1 += UNP1(g.x); c2 += UNP0(g.y); c3 += UNP1(g.y); }
    #define ACCB(g) { e0 += UNP0(g.x); e1 += UNP1(g.x); e2 += UNP0(g.y); e3 += UNP1(g.y); }
    #define GATHER                                                           \
    {                                                                        \
        const unsigned* lw = (const unsigned*)buf;                           \
        int i = 0;                                                           \
        for (; i + 8 <= c; i += 8) {                                         \
            unsigned q0 = lw[(i >> 1)    ];                                  \
            unsigned q1 = lw[(i >> 1) + 1];                                  \
            unsigned q2 = lw[(i >> 1) + 2];                                  \
            unsigned q3 = lw[(i >> 1) + 3];                                  \
            unsigned o0 = (q0 & 0xffffu) * 64u + lane;                       \
            unsigned o1 = (q0 >> 16)     * 64u + lane;                       \
            unsigned o2 = (q1 & 0xffffu) * 64u + lane;                       \
            unsigned o3 = (q1 >> 16)     * 64u + lane;                       \
            unsigned o4 = (q2 & 0xffffu) * 64u + lane;                       \
            unsigned o5 = (q2 >> 16)     * 64u + lane;                       \
            unsigned o6 = (q3 & 0xffffu) * 64u + lane;                       \
            unsigned o7 = (q3 >> 16)     * 64u + lane;                       \
            uint2 g0 = ddp[o0]; uint2 g1 = ddp[o1];                          \
            uint2 g2 = ddp[o2]; uint2 g3 = ddp[o3];                          \
            uint2 g4 = ddp[o4]; uint2 g5 = ddp[o5];                          \
            uint2 g6 = ddp[o6]; uint2 g7 = ddp[o7];                          \
            ACCA(g0) ACCB(g1) ACCA(g2) ACCB(g3)                              \
            ACCA(g4) ACCB(g5) ACCA(g6) ACCB(g7)                              \
        }                                                                    \
        for (; i + 4 <= c; i += 4) {                                         \
            unsigned q0 = lw[(i >> 1)    ];                                  \
            unsigned q1 = lw[(i >> 1) + 1];                                  \
            unsigned o0 = (q0 & 0xffffu) * 64u + lane;                       \
            unsigned o1 = (q0 >> 16)     * 64u + lane;                       \
            unsigned o2 = (q1 & 0xffffu) * 64u + lane;                       \
            unsigned o3 = (q1 >> 16)     * 64u + lane;                       \
            uint2 g0 = ddp[o0]; uint2 g1 = ddp[o1];                          \
            uint2 g2 = ddp[o2]; uint2 g3 = ddp[o3];                          \
            ACCA(g0) ACCB(g1) ACCA(g2) ACCB(g3)                              \
        }                                                                    \
        for (; i < c; ++i) {                                                 \
            unsigned n = buf[i];                                             \
            uint2 g = ddp[n * 64u + lane];                                   \
            ACCA(g)                                                          \
        }                                                                    \
    }
    #define WB __builtin_amdgcn_wave_barrier()

    ISSUE(a, g, 0);                      // prologue: row 0's first half
    #pragma unroll 1
    for (int k = 0; k < 4; ++k) {
        const int m = g + k * 2048;
        if (m >= MM) break;
        float c0 = 0.f, c1 = 0.f, c2 = 0.f, c3 = 0.f;
        float e0 = 0.f, e1 = 0.f, e2 = 0.f, e3 = 0.f;

        ISSUE(b, m, 1);                  // next half in flight during compact+gather
        int c = 0;
        COMPACT(a, 0);
        WB;
        GATHER;
        WB;

        const int mn = m + 2048;
        if (mn < MM) ISSUE(a, mn, 0);    // next row's first half in flight
        c = 0;
        COMPACT(b, 1);
        WB;
        GATHER;
        WB;

        const float wgt = param[parents[m]] - param[m];
        p0 += wgt * fabsf(c0 + e0);
        p1 += wgt * fabsf(c1 + e1);
        p2 += wgt * fabsf(c2 + e2);
        p3 += wgt * fabsf(c3 + e3);
    }
    #undef WB
    #undef GATHER
    #undef ACCA
    #undef ACCB
    #undef UNP0
    #undef UNP1
    #undef COMPACT
    #undef QUAD
    #undef SITE
    #undef ISSUE

    atomicAdd(&s_part[4 * lane + 0], p0);
    atomicAdd(&s_part[4 * lane + 1], p1);
    atomicAdd(&s_part[4 * lane + 2], p2);
    atomicAdd(&s_part[4 * lane + 3], p3);
    __syncthreads();
    atomicAdd(&part2[(size_t)(blockIdx.x & 255) * BB + tid], s_part[tid]);
}

// ---------------------------------------------------------------------------
// k_finalize: 1024 threads. Thread (s,b) sums 64 of the 256 part2 rows
// 8-deep; LDS-reduce the 4 s-slices; out = sum_b (ot[b]-0.5*w1[b])^2.
// ---------------------------------------------------------------------------
__global__ __launch_bounds__(1024) void k_finalize(const float* __restrict__ part2,
                                                   const float* __restrict__ ot,
                                                   float* __restrict__ out) {
    __shared__ float s_red[4][BB];
    __shared__ float s_sq[16];
    const int tid = threadIdx.x;
    const int s = tid >> 8, b = tid & 255;

    float a0 = 0.f, a1 = 0.f, a2 = 0.f, a3 = 0.f;
    float a4 = 0.f, a5 = 0.f, a6 = 0.f, a7 = 0.f;
    #pragma unroll
    for (int j = 0; j < 64; j += 8) {
        int row = s * 64 + j;
        a0 += part2[(row    ) * BB + b];
        a1 += part2[(row + 1) * BB + b];
        a2 += part2[(row + 2) * BB + b];
        a3 += part2[(row + 3) * BB + b];
        a4 += part2[(row + 4) * BB + b];
        a5 += part2[(row + 5) * BB + b];
        a6 += part2[(row + 6) * BB + b];
        a7 += part2[(row + 7) * BB + b];
    }
    s_red[s][b] = ((a0 + a1) + (a2 + a3)) + ((a4 + a5) + (a6 + a7));
    __syncthreads();

    float v = 0.0f;
    if (s == 0) {
        float w1 = (s_red[0][b] + s_red[1][b]) + (s_red[2][b] + s_red[3][b]);
        float e = ot[b] - 0.5f * w1;
        v = e * e;
    }
    #pragma unroll
    for (int off = 32; off > 0; off >>= 1) v += __shfl_down(v, off, 64);
    if ((tid & 63) == 0) s_sq[tid >> 6] = v;
    __syncthreads();
    if (tid == 0) out[0] = (s_sq[0] + s_sq[1]) + (s_sq[2] + s_sq[3]);
}

// ---------------------------------------------------------------------------
extern "C" void kernel_launch(void* const* d_in, const int* in_sizes, int n_in,
                              void* d_out, int out_size, void* d_ws, size_t ws_size,
                              hipStream_t stream) {
    const float* d1      = (const float*)d_in[0];
    const float* d2      = (const float*)d_in[1];
    const float* ot      = (const float*)d_in[2];
    const float* subtree = (const float*)d_in[3];
    const float* param   = (const float*)d_in[4];
    const int*   parents = (const int*)d_in[5];

    char* wsb = (char*)d_ws;
    float* part2 = (float*)wsb;                         // 256*256 f = 256 KB
    uint2* ddp   = (uint2*)(wsb + 256 * BB * 4);        // 2 MB packed bf16

    k_prep<<<1024, 256, 0, stream>>>((const float4*)d1, (const float4*)d2,
                                     part2, ddp);
    k_fused<<<512, 256, 0, stream>>>((const nfloat4*)subtree, ddp,
                                     param, parents, part2);
    k_finalize<<<1, 1024, 0, stream>>>(part2, ot, (float*)d_out);
}

// Round 14
// 51.933 us; speedup vs baseline: 1.0362x; 1.0362x over previous
//
#include <hip/hip_runtime.h>

#define NN    4096
#define MM    8191   // 2*NN - 1
#define BB    256
#define HCAP  128    // u16 slots per HALF-row list (nnz/half ~20, max ~50)

typedef float nfloat4 __attribute__((ext_vector_type(4)));

__device__ __forceinline__ int prefix_lt(unsigned long long m) {
    return __builtin_amdgcn_mbcnt_hi((unsigned)(m >> 32),
           __builtin_amdgcn_mbcnt_lo((unsigned)m, 0u));
}

// round-to-nearest-even pack of two f32 into 2x bf16 in one uint
__device__ __forceinline__ unsigned pack2bf(float lo, float hi) {
    unsigned a = __float_as_uint(lo);
    unsigned b = __float_as_uint(hi);
    a += 0x7fffu + ((a >> 16) & 1u);
    b += 0x7fffu + ((b >> 16) & 1u);
    return (a >> 16) | (b & 0xffff0000u);
}

// ---------------------------------------------------------------------------
// k_prep: zero part2[256*256]; pack dd = bf16(d1-d2) (2 MB). One uint2/thread.
// ---------------------------------------------------------------------------
__global__ __launch_bounds__(256) void k_prep(const float4* __restrict__ d1,
                                              const float4* __restrict__ d2,
                                              float* __restrict__ part2,
                                              uint2* __restrict__ ddp) {
    int idx = blockIdx.x * 256 + threadIdx.x;          // 0..262143
    if (idx < 256 * BB) part2[idx] = 0.0f;
    float4 a = d1[idx], b = d2[idx];
    uint2 r;
    r.x = pack2bf(a.x - b.x, a.y - b.y);
    r.y = pack2bf(a.z - b.z, a.w - b.w);
    ddp[idx] = r;
}

// ---------------------------------------------------------------------------
// k_fused v3 — producer/consumer wave specialization (R13 post-mortem: vmcnt
// retires in order, so one wave can never overlap stream-prefetch with
// later-issued gathers; split the roles across waves instead).
//   waves 0,1: producers — scan+compact only, register double-buffered halves
//              -> pure stream vmcnt -> HBM saturated (standalone compact
//              measured AT the 6.2 TB/s roofline).
//   waves 2,3: consumers — gather only (per-CU request-rate bound, ~20 us
//              chip-wide) -> pure gather vmcnt.
// Handoff: per-pipeline 2-slot LDS ring {lists, counts, flag}; spin +
// s_sleep + __threadfence_block, block-local (co-resident, no deadlock).
// Pipeline pipe=wave&1 of block b owns rows m = 2b+pipe + i*2048, i<4.
// ---------------------------------------------------------------------------
__global__ __launch_bounds__(256, 4) void k_fused(
        const nfloat4* __restrict__ st4,
        const uint2* __restrict__ ddp,
        const float* __restrict__ param,
        const int*   __restrict__ parents,
        float* __restrict__ part2) {
    __shared__ unsigned short s_list[2][2][2][HCAP];   // [pipe][slot][half][..]
    __shared__ int s_cnt[2][2][2];
    __shared__ int s_flag[2][2];                       // 0=free, i+1=filled
    __shared__ float s_part[BB];
    const int tid  = threadIdx.x;
    const int wave = tid >> 6;
    const int lane = tid & 63;

    s_part[tid] = 0.0f;
    if (tid < 4) s_flag[tid >> 1][tid & 1] = 0;
    __syncthreads();

    const int pipe = wave & 1;
    const int base = blockIdx.x * 2 + pipe;            // 0..2047
    float q0 = 0.f, q1 = 0.f, q2 = 0.f, q3 = 0.f;

    if (wave < 2) {
        // ================= PRODUCER =================
        nfloat4 a0, a1, a2, a3, a4, a5, a6, a7;
        nfloat4 b0, b1, b2, b3, b4, b5, b6, b7;

        #define ISSUE(P, m, h)                                                   \
        {                                                                        \
            const nfloat4* gbase = st4 + (size_t)(m) * (NN / 4) + (h) * (NN / 8);\
            P##0 = __builtin_nontemporal_load(gbase + lane);                     \
            P##1 = __builtin_nontemporal_load(gbase + 64  + lane);               \
            P##2 = __builtin_nontemporal_load(gbase + 128 + lane);               \
            P##3 = __builtin_nontemporal_load(gbase + 192 + lane);               \
            P##4 = __builtin_nontemporal_load(gbase + 256 + lane);               \
            P##5 = __builtin_nontemporal_load(gbase + 320 + lane);               \
            P##6 = __builtin_nontemporal_load(gbase + 384 + lane);               \
            P##7 = __builtin_nontemporal_load(gbase + 448 + lane);               \
        }
        #define SITE(val, col)                                                   \
        {                                                                        \
            unsigned long long mk = __ballot((val) != 0.0f);                     \
            if ((val) != 0.0f)                                                   \
                buf[c + prefix_lt(mk)] = (unsigned short)(col);                  \
            c += __popcll(mk);                                                   \
        }
        #define QUAD(v, cb0)                                                     \
            SITE(v.x, (cb0))     SITE(v.y, (cb0) + 1)                            \
            SITE(v.z, (cb0) + 2) SITE(v.w, (cb0) + 3)
        #define COMPACT(P, h)                                                    \
        {                                                                        \
            const int cb = (h) * (NN / 2);                                       \
            QUAD(P##0, cb + (lane)       * 4)                                    \
            QUAD(P##1, cb + (64  + lane) * 4)                                    \
            QUAD(P##2, cb + (128 + lane) * 4)                                    \
            QUAD(P##3, cb + (192 + lane) * 4)                                    \
            QUAD(P##4, cb + (256 + lane) * 4)                                    \
            QUAD(P##5, cb + (320 + lane) * 4)                                    \
            QUAD(P##6, cb + (384 + lane) * 4)                                    \
            QUAD(P##7, cb + (448 + lane) * 4)                                    \
        }

        if (base < MM) ISSUE(a, base, 0);
        #pragma unroll 1
        for (int i = 0; i < 4; ++i) {
            const int m = base + i * 2048;
            if (m >= MM) break;
            const int slot = i & 1;
            ISSUE(b, m, 1);                 // half1 in flight during compact A

            volatile int* f = &s_flag[pipe][slot];
            while (*f != 0) __builtin_amdgcn_s_sleep(2);
            __threadfence_block();

            unsigned short* buf;
            int c;
            buf = s_list[pipe][slot][0]; c = 0;
            COMPACT(a, 0);
            if (lane == 0) s_cnt[pipe][slot][0] = c;

            const int mn = base + (i + 1) * 2048;
            if (mn < MM) ISSUE(a, mn, 0);   // next row's half0 in flight

            buf = s_list[pipe][slot][1]; c = 0;
            COMPACT(b, 1);
            if (lane == 0) s_cnt[pipe][slot][1] = c;

            __threadfence_block();
            if (lane == 0) *f = i + 1;
        }
        #undef COMPACT
        #undef QUAD
        #undef SITE
        #undef ISSUE
    } else {
        // ================= CONSUMER =================
        #define UNP0(u) __uint_as_float((u) << 16)
        #define UNP1(u) __uint_as_float((u) & 0xffff0000u)
        #define ACCA(g) { c0 += UNP0(g.x); c1 += UNP1(g.x); c2 += UNP0(g.y); c3 += UNP1(g.y); }
        #define ACCB(g) { e0 += UNP0(g.x); e1 += UNP1(g.x); e2 += UNP0(g.y); e3 += UNP1(g.y); }
        #pragma unroll 1
        for (int i = 0; i < 4; ++i) {
            const int m = base + i * 2048;
            if (m >= MM) break;
            const int slot = i & 1;
            volatile int* f = &s_flag[pipe][slot];
            while (*f != i + 1) __builtin_amdgcn_s_sleep(2);
            __threadfence_block();

            float c0 = 0.f, c1 = 0.f, c2 = 0.f, c3 = 0.f;
            float e0 = 0.f, e1 = 0.f, e2 = 0.f, e3 = 0.f;
            #pragma unroll
            for (int h = 0; h < 2; ++h) {
                const int c = s_cnt[pipe][slot][h];
                const unsigned short* bufr = s_list[pipe][slot][h];
                const unsigned* lw = (const unsigned*)bufr;
                int j = 0;
                for (; j + 8 <= c; j += 8) {
                    unsigned w0 = lw[(j >> 1)    ];
                    unsigned w1 = lw[(j >> 1) + 1];
                    unsigned w2 = lw[(j >> 1) + 2];
                    unsigned w3 = lw[(j >> 1) + 3];
                    unsigned o0 = (w0 & 0xffffu) * 64u + lane;
                    unsigned o1 = (w0 >> 16)     * 64u + lane;
                    unsigned o2 = (w1 & 0xffffu) * 64u + lane;
                    unsigned o3 = (w1 >> 16)     * 64u + lane;
                    unsigned o4 = (w2 & 0xffffu) * 64u + lane;
                    unsigned o5 = (w2 >> 16)     * 64u + lane;
                    unsigned o6 = (w3 & 0xffffu) * 64u + lane;
                    unsigned o7 = (w3 >> 16)     * 64u + lane;
                    uint2 g0 = ddp[o0]; uint2 g1 = ddp[o1];
                    uint2 g2 = ddp[o2]; uint2 g3 = ddp[o3];
                    uint2 g4 = ddp[o4]; uint2 g5 = ddp[o5];
                    uint2 g6 = ddp[o6]; uint2 g7 = ddp[o7];
                    ACCA(g0) ACCB(g1) ACCA(g2) ACCB(g3)
                    ACCA(g4) ACCB(g5) ACCA(g6) ACCB(g7)
                }
                for (; j + 4 <= c; j += 4) {
                    unsigned w0 = lw[(j >> 1)    ];
                    unsigned w1 = lw[(j >> 1) + 1];
                    unsigned o0 = (w0 & 0xffffu) * 64u + lane;
                    unsigned o1 = (w0 >> 16)     * 64u + lane;
                    unsigned o2 = (w1 & 0xffffu) * 64u + lane;
                    unsigned o3 = (w1 >> 16)     * 64u + lane;
                    uint2 g0 = ddp[o0]; uint2 g1 = ddp[o1];
                    uint2 g2 = ddp[o2]; uint2 g3 = ddp[o3];
                    ACCA(g0) ACCB(g1) ACCA(g2) ACCB(g3)
                }
                for (; j < c; ++j) {
                    unsigned n = bufr[j];
                    uint2 g = ddp[n * 64u + lane];
                    ACCA(g)
                }
            }
            __threadfence_block();
            if (lane == 0) *f = 0;

            const float wgt = param[parents[m]] - param[m];
            q0 += wgt * fabsf(c0 + e0);
            q1 += wgt * fabsf(c1 + e1);
            q2 += wgt * fabsf(c2 + e2);
            q3 += wgt * fabsf(c3 + e3);
        }
        #undef ACCA
        #undef ACCB
        #undef UNP0
        #undef UNP1
    }

    atomicAdd(&s_part[4 * lane + 0], q0);
    atomicAdd(&s_part[4 * lane + 1], q1);
    atomicAdd(&s_part[4 * lane + 2], q2);
    atomicAdd(&s_part[4 * lane + 3], q3);
    __syncthreads();
    atomicAdd(&part2[(size_t)(blockIdx.x & 255) * BB + tid], s_part[tid]);
}

// ---------------------------------------------------------------------------
// k_finalize: 1024 threads. Thread (s,b) sums 64 of the 256 part2 rows
// 8-deep; LDS-reduce the 4 s-slices; out = sum_b (ot[b]-0.5*w1[b])^2.
// ---------------------------------------------------------------------------
__global__ __launch_bounds__(1024) void k_finalize(const float* __restrict__ part2,
                                                   const float* __restrict__ ot,
                                                   float* __restrict__ out) {
    __shared__ float s_red[4][BB];
    __shared__ float s_sq[16];
    const int tid = threadIdx.x;
    const int s = tid >> 8, b = tid & 255;

    float a0 = 0.f, a1 = 0.f, a2 = 0.f, a3 = 0.f;
    float a4 = 0.f, a5 = 0.f, a6 = 0.f, a7 = 0.f;
    #pragma unroll
    for (int j = 0; j < 64; j += 8) {
        int row = s * 64 + j;
        a0 += part2[(row    ) * BB + b];
        a1 += part2[(row + 1) * BB + b];
        a2 += part2[(row + 2) * BB + b];
        a3 += part2[(row + 3) * BB + b];
        a4 += part2[(row + 4) * BB + b];
        a5 += part2[(row + 5) * BB + b];
        a6 += part2[(row + 6) * BB + b];
        a7 += part2[(row + 7) * BB + b];
    }
    s_red[s][b] = ((a0 + a1) + (a2 + a3)) + ((a4 + a5) + (a6 + a7));
    __syncthreads();

    float v = 0.0f;
    if (s == 0) {
        float w1 = (s_red[0][b] + s_red[1][b]) + (s_red[2][b] + s_red[3][b]);
        float e = ot[b] - 0.5f * w1;
        v = e * e;
    }
    #pragma unroll
    for (int off = 32; off > 0; off >>= 1) v += __shfl_down(v, off, 64);
    if ((tid & 63) == 0) s_sq[tid >> 6] = v;
    __syncthreads();
    if (tid == 0) out[0] = (s_sq[0] + s_sq[1]) + (s_sq[2] + s_sq[3]);
}

// ---------------------------------------------------------------------------
extern "C" void kernel_launch(void* const* d_in, const int* in_sizes, int n_in,
                              void* d_out, int out_size, void* d_ws, size_t ws_size,
                              hipStream_t stream) {
    const float* d1      = (const float*)d_in[0];
    const float* d2      = (const float*)d_in[1];
    const float* ot      = (const float*)d_in[2];
    const float* subtree = (const float*)d_in[3];
    const float* param   = (const float*)d_in[4];
    const int*   parents = (const int*)d_in[5];

    char* wsb = (char*)d_ws;
    float* part2 = (float*)wsb;                         // 256*256 f = 256 KB
    uint2* ddp   = (uint2*)(wsb + 256 * BB * 4);        // 2 MB packed bf16

    k_prep<<<1024, 256, 0, stream>>>((const float4*)d1, (const float4*)d2,
                                     part2, ddp);
    k_fused<<<1024, 256, 0, stream>>>((const nfloat4*)subtree, ddp,
                                      param, parents, part2);
    k_finalize<<<1, 1024, 0, stream>>>(part2, ot, (float*)d_out);
}

// Round 15
// 50.425 us; speedup vs baseline: 1.0672x; 1.0299x over previous
//
#include <hip/hip_runtime.h>

#define NN    4096
#define MM    8191   // 2*NN - 1
#define BB    256
#define HCAP  128    // u16 slots per HALF-row list (nnz/half ~20, max ~50)

typedef float nfloat4 __attribute__((ext_vector_type(4)));

__device__ __forceinline__ int prefix_lt(unsigned long long m) {
    return __builtin_amdgcn_mbcnt_hi((unsigned)(m >> 32),
           __builtin_amdgcn_mbcnt_lo((unsigned)m, 0u));
}

// round-to-nearest-even pack of two f32 into 2x bf16 in one uint
__device__ __forceinline__ unsigned pack2bf(float lo, float hi) {
    unsigned a = __float_as_uint(lo);
    unsigned b = __float_as_uint(hi);
    a += 0x7fffu + ((a >> 16) & 1u);
    b += 0x7fffu + ((b >> 16) & 1u);
    return (a >> 16) | (b & 0xffff0000u);
}

// ---------------------------------------------------------------------------
// k_prep: zero part2[256*256]; pack dd = bf16(d1-d2) (2 MB). One uint2/thread.
// ---------------------------------------------------------------------------
__global__ __launch_bounds__(256) void k_prep(const float4* __restrict__ d1,
                                              const float4* __restrict__ d2,
                                              float* __restrict__ part2,
                                              uint2* __restrict__ ddp) {
    int idx = blockIdx.x * 256 + threadIdx.x;          // 0..262143
    if (idx < 256 * BB) part2[idx] = 0.0f;
    float4 a = d1[idx], b = d2[idx];
    uint2 r;
    r.x = pack2bf(a.x - b.x, a.y - b.y);
    r.y = pack2bf(a.z - b.z, a.w - b.w);
    ddp[idx] = r;
}

// ---------------------------------------------------------------------------
// k_fused v4 — producer/consumer at ROOFLINE GEOMETRY (R14 post-mortem: only
// 8 producer waves/CU streamed; the roofline compact had 16).
// 1024 blocks x 512 threads, LB(512,8) -> 4 blocks/CU = 32 waves/CU:
//   waves 0-3: producers (16/CU) — single-buffered half-row scan+compact,
//              pure stream vmcnt. 16 waves x 4KB x ~45% wait-duty = 29 KB
//              in flight per CU >> 9.2 KB HBM saturation threshold.
//   waves 4-7: consumers (16/CU) — pure 8-deep gather from L2-resident dd.
// Pipe p=wave&3 of block b: rows m = (b*4+p) + k*4096, k<2. 2-slot LDS ring.
// ---------------------------------------------------------------------------
__global__ __launch_bounds__(512, 8) void k_fused(
        const nfloat4* __restrict__ st4,
        const uint2* __restrict__ ddp,
        const float* __restrict__ param,
        const int*   __restrict__ parents,
        float* __restrict__ part2) {
    __shared__ unsigned short s_list[4][2][2][HCAP];   // [pipe][slot][half][..]
    __shared__ int s_cnt[4][2][2];
    __shared__ int s_flag[4][2];                       // 0=free, k+1=filled
    __shared__ float s_part[BB];
    const int tid  = threadIdx.x;
    const int wave = tid >> 6;
    const int lane = tid & 63;

    if (tid < BB) s_part[tid] = 0.0f;
    if (tid < 8) s_flag[tid >> 1][tid & 1] = 0;
    __syncthreads();

    const int pipe = wave & 3;
    const int pg   = blockIdx.x * 4 + pipe;            // pipe gid 0..4095
    float q0 = 0.f, q1 = 0.f, q2 = 0.f, q3 = 0.f;

    if (wave < 4) {
        // ================= PRODUCER (single-buffered) =================
        nfloat4 a0, a1, a2, a3, a4, a5, a6, a7;
        #define ISSUE(m, h)                                                      \
        {                                                                        \
            const nfloat4* gb = st4 + (size_t)(m) * (NN / 4) + (h) * (NN / 8);   \
            a0 = __builtin_nontemporal_load(gb + lane);                          \
            a1 = __builtin_nontemporal_load(gb + 64  + lane);                    \
            a2 = __builtin_nontemporal_load(gb + 128 + lane);                    \
            a3 = __builtin_nontemporal_load(gb + 192 + lane);                    \
            a4 = __builtin_nontemporal_load(gb + 256 + lane);                    \
            a5 = __builtin_nontemporal_load(gb + 320 + lane);                    \
            a6 = __builtin_nontemporal_load(gb + 384 + lane);                    \
            a7 = __builtin_nontemporal_load(gb + 448 + lane);                    \
        }
        #define SITE(val, col)                                                   \
        {                                                                        \
            unsigned long long mk = __ballot((val) != 0.0f);                     \
            if ((val) != 0.0f)                                                   \
                buf[c + prefix_lt(mk)] = (unsigned short)(col);                  \
            c += __popcll(mk);                                                   \
        }
        #define QUAD(v, cb0)                                                     \
            SITE(v.x, (cb0))     SITE(v.y, (cb0) + 1)                            \
            SITE(v.z, (cb0) + 2) SITE(v.w, (cb0) + 3)
        #define COMPACT(h)                                                       \
        {                                                                        \
            const int cb = (h) * (NN / 2);                                       \
            QUAD(a0, cb + (lane)       * 4)                                      \
            QUAD(a1, cb + (64  + lane) * 4)                                      \
            QUAD(a2, cb + (128 + lane) * 4)                                      \
            QUAD(a3, cb + (192 + lane) * 4)                                      \
            QUAD(a4, cb + (256 + lane) * 4)                                      \
            QUAD(a5, cb + (320 + lane) * 4)                                      \
            QUAD(a6, cb + (384 + lane) * 4)                                      \
            QUAD(a7, cb + (448 + lane) * 4)                                      \
        }
        #pragma unroll 1
        for (int k = 0; k < 2; ++k) {
            const int m = pg + k * 4096;
            if (m >= MM) break;
            const int slot = k & 1;
            volatile int* f = &s_flag[pipe][slot];

            ISSUE(m, 0);                       // loads in flight during spin
            while (*f != 0) __builtin_amdgcn_s_sleep(2);
            __threadfence_block();

            unsigned short* buf = s_list[pipe][slot][0];
            int c = 0;
            COMPACT(0);
            if (lane == 0) s_cnt[pipe][slot][0] = c;

            ISSUE(m, 1);
            buf = s_list[pipe][slot][1];
            c = 0;
            COMPACT(1);
            if (lane == 0) s_cnt[pipe][slot][1] = c;

            __threadfence_block();
            if (lane == 0) *f = k + 1;
        }
        #undef COMPACT
        #undef QUAD
        #undef SITE
        #undef ISSUE
    } else {
        // ================= CONSUMER =================
        #define UNP0(u) __uint_as_float((u) << 16)
        #define UNP1(u) __uint_as_float((u) & 0xffff0000u)
        #define ACCA(g) { c0 += UNP0(g.x); c1 += UNP1(g.x); c2 += UNP0(g.y); c3 += UNP1(g.y); }
        #define ACCB(g) { e0 += UNP0(g.x); e1 += UNP1(g.x); e2 += UNP0(g.y); e3 += UNP1(g.y); }
        #pragma unroll 1
        for (int k = 0; k < 2; ++k) {
            const int m = pg + k * 4096;
            if (m >= MM) break;
            const int slot = k & 1;
            volatile int* f = &s_flag[pipe][slot];
            while (*f != k + 1) __builtin_amdgcn_s_sleep(2);
            __threadfence_block();

            float c0 = 0.f, c1 = 0.f, c2 = 0.f, c3 = 0.f;
            float e0 = 0.f, e1 = 0.f, e2 = 0.f, e3 = 0.f;
            #pragma unroll
            for (int h = 0; h < 2; ++h) {
                const int c = s_cnt[pipe][slot][h];
                const unsigned short* bufr = s_list[pipe][slot][h];
                const unsigned* lw = (const unsigned*)bufr;
                int j = 0;
                for (; j + 8 <= c; j += 8) {
                    unsigned w0 = lw[(j >> 1)    ];
                    unsigned w1 = lw[(j >> 1) + 1];
                    unsigned w2 = lw[(j >> 1) + 2];
                    unsigned w3 = lw[(j >> 1) + 3];
                    unsigned o0 = (w0 & 0xffffu) * 64u + lane;
                    unsigned o1 = (w0 >> 16)     * 64u + lane;
                    unsigned o2 = (w1 & 0xffffu) * 64u + lane;
                    unsigned o3 = (w1 >> 16)     * 64u + lane;
                    unsigned o4 = (w2 & 0xffffu) * 64u + lane;
                    unsigned o5 = (w2 >> 16)     * 64u + lane;
                    unsigned o6 = (w3 & 0xffffu) * 64u + lane;
                    unsigned o7 = (w3 >> 16)     * 64u + lane;
                    uint2 g0 = ddp[o0]; uint2 g1 = ddp[o1];
                    uint2 g2 = ddp[o2]; uint2 g3 = ddp[o3];
                    uint2 g4 = ddp[o4]; uint2 g5 = ddp[o5];
                    uint2 g6 = ddp[o6]; uint2 g7 = ddp[o7];
                    ACCA(g0) ACCB(g1) ACCA(g2) ACCB(g3)
                    ACCA(g4) ACCB(g5) ACCA(g6) ACCB(g7)
                }
                for (; j + 4 <= c; j += 4) {
                    unsigned w0 = lw[(j >> 1)    ];
                    unsigned w1 = lw[(j >> 1) + 1];
                    unsigned o0 = (w0 & 0xffffu) * 64u + lane;
                    unsigned o1 = (w0 >> 16)     * 64u + lane;
                    unsigned o2 = (w1 & 0xffffu) * 64u + lane;
                    unsigned o3 = (w1 >> 16)     * 64u + lane;
                    uint2 g0 = ddp[o0]; uint2 g1 = ddp[o1];
                    uint2 g2 = ddp[o2]; uint2 g3 = ddp[o3];
                    ACCA(g0) ACCB(g1) ACCA(g2) ACCB(g3)
                }
                for (; j < c; ++j) {
                    unsigned n = bufr[j];
                    uint2 g = ddp[n * 64u + lane];
                    ACCA(g)
                }
            }
            __threadfence_block();
            if (lane == 0) *f = 0;

            const float wgt = param[parents[m]] - param[m];
            q0 += wgt * fabsf(c0 + e0);
            q1 += wgt * fabsf(c1 + e1);
            q2 += wgt * fabsf(c2 + e2);
            q3 += wgt * fabsf(c3 + e3);
        }
        #undef ACCA
        #undef ACCB
        #undef UNP0
        #undef UNP1

        atomicAdd(&s_part[4 * lane + 0], q0);
        atomicAdd(&s_part[4 * lane + 1], q1);
        atomicAdd(&s_part[4 * lane + 2], q2);
        atomicAdd(&s_part[4 * lane + 3], q3);
    }
    __syncthreads();
    if (tid < BB)
        atomicAdd(&part2[(size_t)(blockIdx.x & 255) * BB + tid], s_part[tid]);
}

// ---------------------------------------------------------------------------
// k_finalize: 1024 threads. Thread (s,b) sums 64 of the 256 part2 rows
// 8-deep; LDS-reduce the 4 s-slices; out = sum_b (ot[b]-0.5*w1[b])^2.
// ---------------------------------------------------------------------------
__global__ __launch_bounds__(1024) void k_finalize(const float* __restrict__ part2,
                                                   const float* __restrict__ ot,
                                                   float* __restrict__ out) {
    __shared__ float s_red[4][BB];
    __shared__ float s_sq[16];
    const int tid = threadIdx.x;
    const int s = tid >> 8, b = tid & 255;

    float a0 = 0.f, a1 = 0.f, a2 = 0.f, a3 = 0.f;
    float a4 = 0.f, a5 = 0.f, a6 = 0.f, a7 = 0.f;
    #pragma unroll
    for (int j = 0; j < 64; j += 8) {
        int row = s * 64 + j;
        a0 += part2[(row    ) * BB + b];
        a1 += part2[(row + 1) * BB + b];
        a2 += part2[(row + 2) * BB + b];
        a3 += part2[(row + 3) * BB + b];
        a4 += part2[(row + 4) * BB + b];
        a5 += part2[(row + 5) * BB + b];
        a6 += part2[(row + 6) * BB + b];
        a7 += part2[(row + 7) * BB + b];
    }
    s_red[s][b] = ((a0 + a1) + (a2 + a3)) + ((a4 + a5) + (a6 + a7));
    __syncthreads();

    float v = 0.0f;
    if (s == 0) {
        float w1 = (s_red[0][b] + s_red[1][b]) + (s_red[2][b] + s_red[3][b]);
        float e = ot[b] - 0.5f * w1;
        v = e * e;
    }
    #pragma unroll
    for (int off = 32; off > 0; off >>= 1) v += __shfl_down(v, off, 64);
    if ((tid & 63) == 0) s_sq[tid >> 6] = v;
    __syncthreads();
    if (tid == 0) out[0] = (s_sq[0] + s_sq[1]) + (s_sq[2] + s_sq[3]);
}

// ---------------------------------------------------------------------------
extern "C" void kernel_launch(void* const* d_in, const int* in_sizes, int n_in,
                              void* d_out, int out_size, void* d_ws, size_t ws_size,
                              hipStream_t stream) {
    const float* d1      = (const float*)d_in[0];
    const float* d2      = (const float*)d_in[1];
    const float* ot      = (const float*)d_in[2];
    const float* subtree = (const float*)d_in[3];
    const float* param   = (const float*)d_in[4];
    const int*   parents = (const int*)d_in[5];

    char* wsb = (char*)d_ws;
    float* part2 = (float*)wsb;                         // 256*256 f = 256 KB
    uint2* ddp   = (uint2*)(wsb + 256 * BB * 4);        // 2 MB packed bf16

    k_prep<<<1024, 256, 0, stream>>>((const float4*)d1, (const float4*)d2,
                                     part2, ddp);
    k_fused<<<1024, 512, 0, stream>>>((const nfloat4*)subtree, ddp,
                                      param, parents, part2);
    k_finalize<<<1, 1024, 0, stream>>>(part2, ot, (float*)d_out);
}

// Round 16
// 47.179 us; speedup vs baseline: 1.1407x; 1.0688x over previous
//
#include <hip/hip_runtime.h>
#include <hip/hip_fp8.h>

#define NN    4096
#define MM    8191   // 2*NN - 1
#define BB    256
#define CAP   256    // u16 slots per row

typedef float nfloat4 __attribute__((ext_vector_type(4)));
typedef float f32x2 __attribute__((ext_vector_type(2)));

__device__ __forceinline__ int prefix_lt(unsigned long long m) {
    return __builtin_amdgcn_mbcnt_hi((unsigned)(m >> 32),
           __builtin_amdgcn_mbcnt_lo((unsigned)m, 0u));
}

#if defined(__has_builtin)
#if __has_builtin(__builtin_amdgcn_cvt_pk_fp8_f32) && __has_builtin(__builtin_amdgcn_cvt_pk_f32_fp8)
#define HW_FP8 1
#endif
#endif

// pack 4 f32 -> 4x e4m3 in one uint (cols 0..3 = bytes 0..3)
__device__ __forceinline__ unsigned pack4fp8(float x0, float x1, float x2, float x3) {
#ifdef HW_FP8
    int r = 0;
    r = __builtin_amdgcn_cvt_pk_fp8_f32(x0, x1, r, false);  // low word
    r = __builtin_amdgcn_cvt_pk_fp8_f32(x2, x3, r, true);   // high word
    return (unsigned)r;
#else
    __hip_fp8_e4m3 a(x0), b(x1), c(x2), d(x3);
    return (unsigned)a.__x | ((unsigned)b.__x << 8) |
           ((unsigned)c.__x << 16) | ((unsigned)d.__x << 24);
#endif
}

// ---------------------------------------------------------------------------
// k_prep: zero part2[256*256]; pack dd = fp8_e4m3(d1-d2) (1 MB).
// ---------------------------------------------------------------------------
__global__ __launch_bounds__(256) void k_prep(const float4* __restrict__ d1,
                                              const float4* __restrict__ d2,
                                              float* __restrict__ part2,
                                              unsigned* __restrict__ dd8) {
    int idx = blockIdx.x * 256 + threadIdx.x;          // 0..262143
    if (idx < 256 * BB) part2[idx] = 0.0f;
    float4 a = d1[idx], b = d2[idx];
    dd8[idx] = pack4fp8(a.x - b.x, a.y - b.y, a.z - b.z, a.w - b.w);
}

// ---------------------------------------------------------------------------
// k_fused (R12 serial-fused structure + fp8 gathers): 2048 blocks x 4 waves,
// one wave per row. Scan row (2 halves x 8 float4 nt loads, the 6.2 TB/s
// pattern) -> ballot compaction into per-wave LDS u16 list -> 8-deep DWORD
// gathers from the 1 MB L2-resident fp8 dd (4 lines/gather instead of bf16's
// 8 — R15 post-mortem: the shared per-CU outstanding-line budget is the wall
// that serialized every fused variant at ~40 us).
// ---------------------------------------------------------------------------
__global__ __launch_bounds__(256, 4) void k_fused(
        const nfloat4* __restrict__ st4,
        const unsigned* __restrict__ dd8,
        const float* __restrict__ param,
        const int*   __restrict__ parents,
        float* __restrict__ part2) {
    __shared__ unsigned short s_idx[4][CAP];
    __shared__ float s_part[BB];
    const int tid  = threadIdx.x;
    const int wave = tid >> 6;
    const int lane = tid & 63;
    unsigned short* buf = s_idx[wave];

    s_part[tid] = 0.0f;
    __syncthreads();

    const int m = blockIdx.x * 4 + wave;
    if (m < MM) {
        // ---- scan + compact ----------------------------------------------
        int c = 0;
        #pragma unroll
        for (int h = 0; h < 2; ++h) {
            const nfloat4* base = st4 + (size_t)m * (NN / 4) + h * (NN / 8);
            nfloat4 v0 = __builtin_nontemporal_load(base + lane);
            nfloat4 v1 = __builtin_nontemporal_load(base + 64  + lane);
            nfloat4 v2 = __builtin_nontemporal_load(base + 128 + lane);
            nfloat4 v3 = __builtin_nontemporal_load(base + 192 + lane);
            nfloat4 v4 = __builtin_nontemporal_load(base + 256 + lane);
            nfloat4 v5 = __builtin_nontemporal_load(base + 320 + lane);
            nfloat4 v6 = __builtin_nontemporal_load(base + 384 + lane);
            nfloat4 v7 = __builtin_nontemporal_load(base + 448 + lane);

            const int cb = h * (NN / 2);
            #define SITE(val, col)                                          \
            {                                                               \
                unsigned long long mk = __ballot((val) != 0.0f);            \
                if ((val) != 0.0f)                                          \
                    buf[c + prefix_lt(mk)] = (unsigned short)(col);         \
                c += __popcll(mk);                                          \
            }
            #define QUAD(v, cb0)                                            \
                SITE(v.x, (cb0))     SITE(v.y, (cb0) + 1)                   \
                SITE(v.z, (cb0) + 2) SITE(v.w, (cb0) + 3)
            QUAD(v0, cb + (lane)       * 4)
            QUAD(v1, cb + (64  + lane) * 4)
            QUAD(v2, cb + (128 + lane) * 4)
            QUAD(v3, cb + (192 + lane) * 4)
            QUAD(v4, cb + (256 + lane) * 4)
            QUAD(v5, cb + (320 + lane) * 4)
            QUAD(v6, cb + (384 + lane) * 4)
            QUAD(v7, cb + (448 + lane) * 4)
            #undef QUAD
            #undef SITE
        }
        __builtin_amdgcn_wave_barrier();

        // ---- gather (fp8, 8-deep) ----------------------------------------
        float c0 = 0.f, c1 = 0.f, c2 = 0.f, c3 = 0.f;
        float e0 = 0.f, e1 = 0.f, e2 = 0.f, e3 = 0.f;
#ifdef HW_FP8
        #define DEC(u, j0, j1, j2, j3)                                       \
        {                                                                    \
            f32x2 lo = __builtin_amdgcn_cvt_pk_f32_fp8((int)(u), false);     \
            f32x2 hi = __builtin_amdgcn_cvt_pk_f32_fp8((int)(u), true);      \
            j0 += lo.x; j1 += lo.y; j2 += hi.x; j3 += hi.y;                  \
        }
#else
        #define DEC(u, j0, j1, j2, j3)                                       \
        {                                                                    \
            __hip_fp8_e4m3 q0, q1, q2, q3;                                   \
            q0.__x = (unsigned char)(u);                                     \
            q1.__x = (unsigned char)((u) >> 8);                              \
            q2.__x = (unsigned char)((u) >> 16);                             \
            q3.__x = (unsigned char)((u) >> 24);                             \
            j0 += (float)q0; j1 += (float)q1; j2 += (float)q2; j3 += (float)q3; \
        }
#endif
        #define ACCA(u) DEC(u, c0, c1, c2, c3)
        #define ACCB(u) DEC(u, e0, e1, e2, e3)
        const unsigned* lw = (const unsigned*)buf;
        int i = 0;
        for (; i + 8 <= c; i += 8) {
            unsigned q0 = lw[(i >> 1)    ];
            unsigned q1 = lw[(i >> 1) + 1];
            unsigned q2 = lw[(i >> 1) + 2];
            unsigned q3 = lw[(i >> 1) + 3];
            unsigned g0 = dd8[(q0 & 0xffffu) * 64u + lane];
            unsigned g1 = dd8[(q0 >> 16)     * 64u + lane];
            unsigned g2 = dd8[(q1 & 0xffffu) * 64u + lane];
            unsigned g3 = dd8[(q1 >> 16)     * 64u + lane];
            unsigned g4 = dd8[(q2 & 0xffffu) * 64u + lane];
            unsigned g5 = dd8[(q2 >> 16)     * 64u + lane];
            unsigned g6 = dd8[(q3 & 0xffffu) * 64u + lane];
            unsigned g7 = dd8[(q3 >> 16)     * 64u + lane];
            ACCA(g0) ACCB(g1) ACCA(g2) ACCB(g3)
            ACCA(g4) ACCB(g5) ACCA(g6) ACCB(g7)
        }
        for (; i + 4 <= c; i += 4) {
            unsigned q0 = lw[(i >> 1)    ];
            unsigned q1 = lw[(i >> 1) + 1];
            unsigned g0 = dd8[(q0 & 0xffffu) * 64u + lane];
            unsigned g1 = dd8[(q0 >> 16)     * 64u + lane];
            unsigned g2 = dd8[(q1 & 0xffffu) * 64u + lane];
            unsigned g3 = dd8[(q1 >> 16)     * 64u + lane];
            ACCA(g0) ACCB(g1) ACCA(g2) ACCB(g3)
        }
        for (; i < c; ++i) {
            unsigned g = dd8[(unsigned)buf[i] * 64u + lane];
            ACCA(g)
        }
        #undef ACCA
        #undef ACCB
        #undef DEC

        const float wgt = param[parents[m]] - param[m];
        atomicAdd(&s_part[4 * lane + 0], wgt * fabsf(c0 + e0));
        atomicAdd(&s_part[4 * lane + 1], wgt * fabsf(c1 + e1));
        atomicAdd(&s_part[4 * lane + 2], wgt * fabsf(c2 + e2));
        atomicAdd(&s_part[4 * lane + 3], wgt * fabsf(c3 + e3));
    }
    __syncthreads();
    atomicAdd(&part2[(size_t)(blockIdx.x & 255) * BB + tid], s_part[tid]);
}

// ---------------------------------------------------------------------------
// k_finalize: 1024 threads; (s,b) sums 64 of 256 part2 rows 8-deep; LDS-
// reduce s-slices; out = sum_b (ot[b]-0.5*w1[b])^2.
// ---------------------------------------------------------------------------
__global__ __launch_bounds__(1024) void k_finalize(const float* __restrict__ part2,
                                                   const float* __restrict__ ot,
                                                   float* __restrict__ out) {
    __shared__ float s_red[4][BB];
    __shared__ float s_sq[16];
    const int tid = threadIdx.x;
    const int s = tid >> 8, b = tid & 255;

    float a0 = 0.f, a1 = 0.f, a2 = 0.f, a3 = 0.f;
    float a4 = 0.f, a5 = 0.f, a6 = 0.f, a7 = 0.f;
    #pragma unroll
    for (int j = 0; j < 64; j += 8) {
        int row = s * 64 + j;
        a0 += part2[(row    ) * BB + b];
        a1 += part2[(row + 1) * BB + b];
        a2 += part2[(row + 2) * BB + b];
        a3 += part2[(row + 3) * BB + b];
        a4 += part2[(row + 4) * BB + b];
        a5 += part2[(row + 5) * BB + b];
        a6 += part2[(row + 6) * BB + b];
        a7 += part2[(row + 7) * BB + b];
    }
    s_red[s][b] = ((a0 + a1) + (a2 + a3)) + ((a4 + a5) + (a6 + a7));
    __syncthreads();

    float v = 0.0f;
    if (s == 0) {
        float w1 = (s_red[0][b] + s_red[1][b]) + (s_red[2][b] + s_red[3][b]);
        float e = ot[b] - 0.5f * w1;
        v = e * e;
    }
    #pragma unroll
    for (int off = 32; off > 0; off >>= 1) v += __shfl_down(v, off, 64);
    if ((tid & 63) == 0) s_sq[tid >> 6] = v;
    __syncthreads();
    if (tid == 0) out[0] = (s_sq[0] + s_sq[1]) + (s_sq[2] + s_sq[3]);
}

// ---------------------------------------------------------------------------
extern "C" void kernel_launch(void* const* d_in, const int* in_sizes, int n_in,
                              void* d_out, int out_size, void* d_ws, size_t ws_size,
                              hipStream_t stream) {
    const float* d1      = (const float*)d_in[0];
    const float* d2      = (const float*)d_in[1];
    const float* ot      = (const float*)d_in[2];
    const float* subtree = (const float*)d_in[3];
    const float* param   = (const float*)d_in[4];
    const int*   parents = (const int*)d_in[5];

    char* wsb = (char*)d_ws;
    float* part2   = (float*)wsb;                       // 256*256 f = 256 KB
    unsigned* dd8  = (unsigned*)(wsb + 256 * BB * 4);   // 1 MB packed fp8

    k_prep<<<1024, 256, 0, stream>>>((const float4*)d1, (const float4*)d2,
                                     part2, dd8);
    k_fused<<<2048, 256, 0, stream>>>((const nfloat4*)subtree, dd8,
                                      param, parents, part2);
    k_finalize<<<1, 1024, 0, stream>>>(part2, ot, (float*)d_out);
}